// Round 3
// baseline (370.454 us; speedup 1.0000x reference)
//
#include <hip/hip_runtime.h>
#include <math.h>

// Shapes (fixed): q(8,256,128,128) c_t(8,256,512) W_a(512,256) W_p(256,512) V_p(2,256)
#define Bq 8
#define Tt 256
#define Dd 256
#define Hh 128
#define Ww 128
#define Cc 512
#define HW (Hh*Ww)
#define NBT (Bq*Tt)   // 2048 tokens

// ---------------- Kernel 0: transpose W_p (256x512) -> WpT (512x256) ------
__global__ __launch_bounds__(256) void transpose_wp(
    const float* __restrict__ W_p, float* __restrict__ WpT)
{
    __shared__ float tile[32][33];
    const int bx = blockIdx.x;            // c tile (16)
    const int by = blockIdx.y;            // p tile (8)
    const int lx = threadIdx.x & 31, ly = threadIdx.x >> 5;   // 32 x 8
#pragma unroll
    for (int j = 0; j < 4; j++) {
        int p = by * 32 + ly + j * 8;
        tile[ly + j * 8][lx] = W_p[(size_t)p * Cc + bx * 32 + lx];
    }
    __syncthreads();
#pragma unroll
    for (int j = 0; j < 4; j++) {
        int c = bx * 32 + ly + j * 8;
        WpT[(size_t)c * 256 + by * 32 + lx] = tile[lx][ly + j * 8];
    }
}

// ---------------- Kernel 1: u = c_t@W_a, p_t = 128*sig(V_p tanh(W_p c)) ---
// 1024 threads = (c-half) x (512 output cols); 16 waves/CU. Each thread
// accumulates its c-half; halves combined via LDS. c_t rows read through
// wave-uniform addresses -> scalar loads (SMEM pipe).
#define TOK 8
__global__ __launch_bounds__(1024) void prep_kernel(
    const float* __restrict__ c_t,   // (NBT, 512)
    const float* __restrict__ W_a,   // (512, 256)  [c][d]
    const float* __restrict__ WpT,   // (512, 256)  [c][p]
    const float* __restrict__ V_p,   // (2, 256)
    float* __restrict__ u_ws,        // (NBT, 256)
    float* __restrict__ p_ws)        // (NBT, 2)
{
    __shared__ float part[TOK][512];     // 16 KB: c-upper-half partials
    __shared__ float y0s[TOK][256];      // 8 KB
    __shared__ float y1s[TOK][256];      // 8 KB
    const int tid   = threadIdx.x;
    const int col   = tid & 511;         // 0..255: u col, 256..511: h col
    const int chalf = tid >> 9;
    const int bt0   = blockIdx.x * TOK;

    const int  colIn = col & 255;
    const float* Wm  = (col < 256) ? W_a : WpT;
    const float* Wcol = Wm + colIn;
    const float* ct0  = c_t + (size_t)bt0 * Cc + chalf * 256;
    const int c0 = chalf * 256;

    float acc[TOK];
#pragma unroll
    for (int t = 0; t < TOK; t++) acc[t] = 0.f;

    for (int c = 0; c < 256; c += 4) {
        float w0 = Wcol[(size_t)(c0 + c + 0) * 256];
        float w1 = Wcol[(size_t)(c0 + c + 1) * 256];
        float w2 = Wcol[(size_t)(c0 + c + 2) * 256];
        float w3 = Wcol[(size_t)(c0 + c + 3) * 256];
#pragma unroll
        for (int t = 0; t < TOK; t++) {
            const float* r = ct0 + t * Cc + c;    // wave-uniform -> s_load
            acc[t] = fmaf(r[0], w0, acc[t]);
            acc[t] = fmaf(r[1], w1, acc[t]);
            acc[t] = fmaf(r[2], w2, acc[t]);
            acc[t] = fmaf(r[3], w3, acc[t]);
        }
    }

    if (chalf == 1) {
#pragma unroll
        for (int t = 0; t < TOK; t++) part[t][col] = acc[t];
    }
    __syncthreads();

    if (chalf == 0) {
        if (col < 256) {
#pragma unroll
            for (int t = 0; t < TOK; t++)
                u_ws[(size_t)(bt0 + t) * Dd + col] = acc[t] + part[t][col];
        } else {
            float v0 = V_p[colIn], v1 = V_p[256 + colIn];
#pragma unroll
            for (int t = 0; t < TOK; t++) {
                float th = tanhf(acc[t] + part[t][col]);
                y0s[t][colIn] = th * v0;
                y1s[t][colIn] = th * v1;
            }
        }
    }
    __syncthreads();

    // 16 waves: waves 0..7 reduce y0 for token w, waves 8..15 reduce y1.
    const int wv = tid >> 6, ln = tid & 63;
    const int t  = wv & 7;
    const float* ys = (wv < 8) ? &y0s[t][0] : &y1s[t][0];
    float s = ys[ln] + ys[ln + 64] + ys[ln + 128] + ys[ln + 192];
#pragma unroll
    for (int of = 32; of >= 1; of >>= 1) s += __shfl_xor(s, of);
    if (ln == 0)
        p_ws[(size_t)(bt0 + t) * 2 + ((wv < 8) ? 0 : 1)] = 128.f / (1.f + expf(-s));
}

// ---------------- Kernel 2: gather + scores + softmax + output ------------
// One block per token, tiny LDS (~4 KB) -> 8 blocks/CU co-resident.
// Pass 1: 243 lanes, 5 independent loads in flight. Pass 2 re-reads q
// (L1/L2-warm) in batches of 9 independent loads.
__global__ __launch_bounds__(256) void attn_kernel(
    const float* __restrict__ q,     // (8,256,128,128)
    const float* __restrict__ u_ws,  // (NBT,256)
    const float* __restrict__ p_ws,  // (NBT,2)
    float* __restrict__ out)         // (NBT,256)
{
    __shared__ float u_s[Dd];
    __shared__ float a_red[243];
    __shared__ int   off_s[81];
    __shared__ float w_s[81];
    __shared__ float a_s[81];
    __shared__ float e_s[81];
    __shared__ float rex_s[9], cex_s[9];
    __shared__ int   rr_s[9], cc_s[9];
    __shared__ float m_sh, inv_sh;

    const int tid = threadIdx.x;
    int bt = blockIdx.x;
    bt = ((bt & 7) << 8) | (bt >> 3);    // batch b -> XCD b (L2 affinity)
    const int b = bt >> 8;

    u_s[tid] = u_ws[(size_t)bt * Dd + tid];

    if (tid < 18) {
        int   i = (tid < 9) ? tid : tid - 9;
        float p = p_ws[(size_t)bt * 2 + ((tid < 9) ? 0 : 1)];
        int base = (int)rintf(p);                 // round-half-even = jnp.round
        int v = base + i - 3;                     // round(p)+off+1, off=i-4
        v = min(max(v, 0), 129) % 129;
        float cl = (float)max(v - 1, 0);
        float z  = (cl - p) * 0.25f;
        float ex = -2.f * z * z;
        if (tid < 9) { rr_s[i] = v; rex_s[i] = ex; }
        else         { cc_s[i] = v; cex_s[i] = ex; }
    }
    __syncthreads();

    if (tid < 81) {
        int i = (tid * 57) >> 9;                  // tid/9
        int j = tid - i * 9;
        int r = rr_s[i], c = cc_s[j];
        bool valid = (r > 0) && (c > 0);
        off_s[tid] = valid ? ((r - 1) * Ww + (c - 1)) : -1;
    }
    __syncthreads();

    // ---- pass 1: a_k = sum_d qg[k,d]*u[d]; lane=(k, s=d%3), 5-deep ----
    if (tid < 243) {
        const int k = tid % 81;
        const int s = tid / 81;
        const int o = max(off_s[k], 0);
        const float* qp = q + ((size_t)(b * Dd + s)) * HW + o;
        const size_t st = (size_t)3 * HW;
        float ap = 0.f;
        int d = s;
        if (s == 0) {                              // peel d=0: all lanes do 85
            ap = fmaf(qp[0], u_s[0], ap);
            qp += st; d = 3;
        }
        for (int it = 0; it < 17; it++) {          // 17 x 5 = 85
            float x0 = qp[0];
            float x1 = qp[st];
            float x2 = qp[2 * st];
            float x3 = qp[3 * st];
            float x4 = qp[4 * st];
            ap = fmaf(x0, u_s[d     ], ap);
            ap = fmaf(x1, u_s[d + 3 ], ap);
            ap = fmaf(x2, u_s[d + 6 ], ap);
            ap = fmaf(x3, u_s[d + 9 ], ap);
            ap = fmaf(x4, u_s[d + 12], ap);
            qp += 5 * st;
            d  += 15;
        }
        a_red[tid] = ap;
    }
    __syncthreads();

    float a_val = -INFINITY;
    bool  valid_k = false;
    if (tid < 81) {
        valid_k = (off_s[tid] >= 0);
        float a = a_red[tid] + a_red[tid + 81] + a_red[tid + 162];
        a_val = valid_k ? a : -INFINITY;
        a_s[tid] = a_val;
    }
    __syncthreads();

    // ---- softmax over 81 (wave-0 butterfly) ----
    if (tid < 64) {
        float m = a_s[tid];
        if (tid + 64 < 81) m = fmaxf(m, a_s[tid + 64]);
        for (int o = 32; o >= 1; o >>= 1) m = fmaxf(m, __shfl_xor(m, o));
        if (tid == 0) m_sh = m;
    }
    __syncthreads();
    {
        float e = 0.f;
        if (tid < 81 && valid_k) e = expf(a_val - m_sh);
        if (tid < 81) e_s[tid] = e;
    }
    __syncthreads();
    if (tid < 64) {
        float sv = e_s[tid] + ((tid + 64 < 81) ? e_s[tid + 64] : 0.f);
        for (int o = 32; o >= 1; o >>= 1) sv += __shfl_xor(sv, o);
        if (tid == 0) inv_sh = 1.f / sv;
    }
    __syncthreads();
    if (tid < 81) {
        int i = (tid * 57) >> 9;
        int j = tid - i * 9;
        float g = expf(rex_s[i] + cex_s[j]);
        w_s[tid] = e_s[tid] * inv_sh * g;
    }
    __syncthreads();

    // ---- pass 2: out[d] = sum_k w_k * q[off_k] in batches of 9 loads ----
    const float* qb = q + ((size_t)(b * Dd + tid)) * HW;
    float acc = 0.f;
    for (int kk = 0; kk < 81; kk += 9) {
        float x0 = qb[max(off_s[kk    ], 0)];
        float x1 = qb[max(off_s[kk + 1], 0)];
        float x2 = qb[max(off_s[kk + 2], 0)];
        float x3 = qb[max(off_s[kk + 3], 0)];
        float x4 = qb[max(off_s[kk + 4], 0)];
        float x5 = qb[max(off_s[kk + 5], 0)];
        float x6 = qb[max(off_s[kk + 6], 0)];
        float x7 = qb[max(off_s[kk + 7], 0)];
        float x8 = qb[max(off_s[kk + 8], 0)];
        acc = fmaf(w_s[kk    ], x0, acc);
        acc = fmaf(w_s[kk + 1], x1, acc);
        acc = fmaf(w_s[kk + 2], x2, acc);
        acc = fmaf(w_s[kk + 3], x3, acc);
        acc = fmaf(w_s[kk + 4], x4, acc);
        acc = fmaf(w_s[kk + 5], x5, acc);
        acc = fmaf(w_s[kk + 6], x6, acc);
        acc = fmaf(w_s[kk + 7], x7, acc);
        acc = fmaf(w_s[kk + 8], x8, acc);
    }
    out[(size_t)bt * Dd + tid] = acc;
}

extern "C" void kernel_launch(void* const* d_in, const int* in_sizes, int n_in,
                              void* d_out, int out_size, void* d_ws, size_t ws_size,
                              hipStream_t stream) {
    const float* q   = (const float*)d_in[0];
    const float* c_t = (const float*)d_in[1];
    const float* W_a = (const float*)d_in[2];
    const float* W_p = (const float*)d_in[3];
    const float* V_p = (const float*)d_in[4];
    float* out  = (float*)d_out;
    float* u_ws = (float*)d_ws;                       // 2 MB
    float* p_ws = u_ws + (size_t)NBT * Dd;            // 16 KB
    float* WpT  = p_ws + (size_t)NBT * 2;             // 512 KB

    transpose_wp<<<dim3(16, 8), 256, 0, stream>>>(W_p, WpT);
    prep_kernel<<<NBT / TOK, 1024, 0, stream>>>(c_t, W_a, WpT, V_p, u_ws, p_ws);
    attn_kernel<<<NBT, 256, 0, stream>>>(q, u_ws, p_ws, out);
}

// Round 4
// 267.797 us; speedup vs baseline: 1.3833x; 1.3833x over previous
//
#include <hip/hip_runtime.h>
#include <math.h>

// Shapes (fixed): q(8,256,128,128) c_t(8,256,512) W_a(512,256) W_p(256,512) V_p(2,256)
#define Bq 8
#define Tt 256
#define Dd 256
#define Hh 128
#define Ww 128
#define Cc 512
#define HW (Hh*Ww)
#define NBT (Bq*Tt)   // 2048 tokens

// ---------------- Kernel 0: transpose W_p (256x512) -> WpT (512x256) ------
__global__ __launch_bounds__(256) void transpose_wp(
    const float* __restrict__ W_p, float* __restrict__ WpT)
{
    __shared__ float tile[32][33];
    const int bx = blockIdx.x;            // c tile (16)
    const int by = blockIdx.y;            // p tile (8)
    const int lx = threadIdx.x & 31, ly = threadIdx.x >> 5;   // 32 x 8
#pragma unroll
    for (int j = 0; j < 4; j++) {
        int p = by * 32 + ly + j * 8;
        tile[ly + j * 8][lx] = W_p[(size_t)p * Cc + bx * 32 + lx];
    }
    __syncthreads();
#pragma unroll
    for (int j = 0; j < 4; j++) {
        int c = bx * 32 + ly + j * 8;
        WpT[(size_t)c * 256 + by * 32 + lx] = tile[lx][ly + j * 8];
    }
}

// ---------------- Kernel 1: u = c_t@W_a, p_t = 128*sig(V_p tanh(W_p c)) ---
// Round-2 proven structure (512 thr), c-unrolled x8 for 8 loads in flight.
#define TOK 8
__global__ __launch_bounds__(512) void prep_kernel(
    const float* __restrict__ c_t,   // (NBT, 512)
    const float* __restrict__ W_a,   // (512, 256)  [c][d]
    const float* __restrict__ WpT,   // (512, 256)  [c][p]
    const float* __restrict__ V_p,   // (2, 256)
    float* __restrict__ u_ws,        // (NBT, 256)
    float* __restrict__ p_ws)        // (NBT, 2)
{
    __shared__ float y0s[TOK][256];
    __shared__ float y1s[TOK][256];
    const int tid  = threadIdx.x;
    const int o    = tid & 255;
    const int half = tid >> 8;
    const int bt0  = blockIdx.x * TOK;

    const float* Wcol = (half ? WpT : W_a) + o;   // column o, stride 256
    const float* ct0  = c_t + (size_t)bt0 * Cc;

    float acc[TOK];
#pragma unroll
    for (int t = 0; t < TOK; t++) acc[t] = 0.f;

    for (int c = 0; c < Cc; c += 8) {
        float w0 = Wcol[(size_t)(c + 0) * 256];
        float w1 = Wcol[(size_t)(c + 1) * 256];
        float w2 = Wcol[(size_t)(c + 2) * 256];
        float w3 = Wcol[(size_t)(c + 3) * 256];
        float w4 = Wcol[(size_t)(c + 4) * 256];
        float w5 = Wcol[(size_t)(c + 5) * 256];
        float w6 = Wcol[(size_t)(c + 6) * 256];
        float w7 = Wcol[(size_t)(c + 7) * 256];
#pragma unroll
        for (int t = 0; t < TOK; t++) {
            const float* r = ct0 + t * Cc + c;    // wave-uniform -> s_load
            acc[t] = fmaf(r[0], w0, acc[t]);
            acc[t] = fmaf(r[1], w1, acc[t]);
            acc[t] = fmaf(r[2], w2, acc[t]);
            acc[t] = fmaf(r[3], w3, acc[t]);
            acc[t] = fmaf(r[4], w4, acc[t]);
            acc[t] = fmaf(r[5], w5, acc[t]);
            acc[t] = fmaf(r[6], w6, acc[t]);
            acc[t] = fmaf(r[7], w7, acc[t]);
        }
    }

    if (half == 0) {
#pragma unroll
        for (int t = 0; t < TOK; t++)
            u_ws[(size_t)(bt0 + t) * Dd + o] = acc[t];
    } else {
        float v0 = V_p[o], v1 = V_p[256 + o];
#pragma unroll
        for (int t = 0; t < TOK; t++) {
            float th = tanhf(acc[t]);
            y0s[t][o] = th * v0;
            y1s[t][o] = th * v1;
        }
    }
    __syncthreads();

    const int wv = tid >> 6, ln = tid & 63;
    float s0 = y0s[wv][ln] + y0s[wv][ln + 64] + y0s[wv][ln + 128] + y0s[wv][ln + 192];
    float s1 = y1s[wv][ln] + y1s[wv][ln + 64] + y1s[wv][ln + 128] + y1s[wv][ln + 192];
#pragma unroll
    for (int of = 32; of >= 1; of >>= 1) {
        s0 += __shfl_xor(s0, of);
        s1 += __shfl_xor(s1, of);
    }
    if (ln == 0) {
        p_ws[(size_t)(bt0 + wv) * 2 + 0] = 128.f / (1.f + expf(-s0));
        p_ws[(size_t)(bt0 + wv) * 2 + 1] = 128.f / (1.f + expf(-s1));
    }
}

// ---------------- Kernel 2: gather + scores + softmax + output ------------
// One block per token. Coalesced float4 row loader -> fp16 LDS stash;
// scores and output both read the stash (no strided/scattered global reads).
__global__ __launch_bounds__(256) void attn_kernel(
    const float* __restrict__ q,     // (8,256,128,128)
    const float* __restrict__ u_ws,  // (NBT,256)
    const float* __restrict__ p_ws,  // (NBT,2)
    float* __restrict__ out)         // (NBT,256)
{
    __shared__ __align__(16) _Float16 win[Dd][9][12];   // 55296 B
    __shared__ float u_s[Dd];
    __shared__ float a_red[243];
    __shared__ float w_s[81];
    __shared__ float a_s[81];
    __shared__ float e_s[81];
    __shared__ float rex_s[9], cex_s[9];
    __shared__ int   rr_s[9], cc_s[9];
    __shared__ float m_sh, inv_sh;

    const int tid = threadIdx.x;
    int bt = blockIdx.x;
    bt = ((bt & 7) << 8) | (bt >> 3);    // batch b -> XCD b (L2 affinity)
    const int b = bt >> 8;

    u_s[tid] = u_ws[(size_t)bt * Dd + tid];

    // zero-fill stash (avoid stale-LDS NaN patterns under w=0)
    {
        float4* wf = (float4*)&win[0][0][0];
        for (int i = tid; i < (int)(sizeof(win) / 16); i += 256) {
            wf[i] = make_float4(0.f, 0.f, 0.f, 0.f);
        }
    }

    if (tid < 18) {
        int   i = (tid < 9) ? tid : tid - 9;
        float p = p_ws[(size_t)bt * 2 + ((tid < 9) ? 0 : 1)];
        int base = (int)rintf(p);                 // round-half-even = jnp.round
        int v = base + i - 3;                     // round(p)+off+1, off=i-4
        v = min(max(v, 0), 129) % 129;
        float cl = (float)max(v - 1, 0);
        float z  = (cl - p) * 0.25f;
        float ex = -2.f * z * z;
        if (tid < 9) { rr_s[i] = v; rex_s[i] = ex; }
        else         { cc_s[i] = v; cex_s[i] = ex; }
    }
    __syncthreads();

    // Valid cols form one contiguous run: derive aligned load base (uniform).
    int jc0 = 0, c0 = 1;
#pragma unroll
    for (int j = 8; j >= 0; j--)
        if (cc_s[j] > 0) { jc0 = j; c0 = cc_s[j]; }
    const int cb = min((c0 - 1) & ~3, Ww - 12);   // 12-float window covers run
    const int e0 = (c0 - 1) - cb;

    // ---- loader: lane=(d-group, row, vec) loads float4, stores fp16 ----
    {
        const int g  = tid >> 5;                  // 0..7 : d offset within group
        const int l5 = tid & 31;
        const bool lact = (l5 < 27);
        const int li = lact ? ((l5 * 171) >> 9) : 0;   // l5/3
        const int lv = l5 - li * 3;
        const int vr = lact ? rr_s[li] : 0;
        const int rowoff = (max(vr, 1) - 1) * Ww + cb + 4 * lv;
        const float* qb = q + (size_t)b * Dd * HW;
        if (lact && vr > 0) {
            for (int dd = 0; dd < Dd; dd += 32) {
                const int d0 = dd + g;
                float4 x0 = *(const float4*)(qb + (size_t)(d0     ) * HW + rowoff);
                float4 x1 = *(const float4*)(qb + (size_t)(d0 +  8) * HW + rowoff);
                float4 x2 = *(const float4*)(qb + (size_t)(d0 + 16) * HW + rowoff);
                float4 x3 = *(const float4*)(qb + (size_t)(d0 + 24) * HW + rowoff);
                union { _Float16 h[4]; uint2 u; } p0, p1, p2, p3;
                p0.h[0] = (_Float16)x0.x; p0.h[1] = (_Float16)x0.y;
                p0.h[2] = (_Float16)x0.z; p0.h[3] = (_Float16)x0.w;
                p1.h[0] = (_Float16)x1.x; p1.h[1] = (_Float16)x1.y;
                p1.h[2] = (_Float16)x1.z; p1.h[3] = (_Float16)x1.w;
                p2.h[0] = (_Float16)x2.x; p2.h[1] = (_Float16)x2.y;
                p2.h[2] = (_Float16)x2.z; p2.h[3] = (_Float16)x2.w;
                p3.h[0] = (_Float16)x3.x; p3.h[1] = (_Float16)x3.y;
                p3.h[2] = (_Float16)x3.z; p3.h[3] = (_Float16)x3.w;
                *(uint2*)&win[d0     ][li][4 * lv] = p0.u;
                *(uint2*)&win[d0 +  8][li][4 * lv] = p1.u;
                *(uint2*)&win[d0 + 16][li][4 * lv] = p2.u;
                *(uint2*)&win[d0 + 24][li][4 * lv] = p3.u;
            }
        }
    }
    __syncthreads();

    // ---- scores from LDS: a_k = sum_d win[d][k]*u[d]; lane=(k, s=d%3) ----
    if (tid < 243) {
        const int k  = tid % 81;
        const int s  = tid / 81;
        const int ki = (k * 57) >> 9;             // k/9
        const int kj = k - ki * 9;
        const int pos = min(max(e0 + kj - jc0, 0), 11);
        const _Float16* wp = &win[0][ki][pos];
        float ap = 0.f;
        int d = s;
        if (s == 0) {                              // peel d=0: all lanes do 85
            ap = fmaf((float)wp[0], u_s[0], ap);
            d = 3;
        }
        const _Float16* w = wp + (size_t)d * 108;
        for (int it = 0; it < 17; it++) {          // 17 x 5 = 85
            float x0 = (float)w[0];
            float x1 = (float)w[3 * 108];
            float x2 = (float)w[6 * 108];
            float x3 = (float)w[9 * 108];
            float x4 = (float)w[12 * 108];
            ap = fmaf(x0, u_s[d     ], ap);
            ap = fmaf(x1, u_s[d + 3 ], ap);
            ap = fmaf(x2, u_s[d + 6 ], ap);
            ap = fmaf(x3, u_s[d + 9 ], ap);
            ap = fmaf(x4, u_s[d + 12], ap);
            w += 15 * 108;
            d += 15;
        }
        a_red[tid] = ap;
    }
    __syncthreads();

    float a_val = -INFINITY;
    bool  valid_k = false;
    if (tid < 81) {
        const int ki = (tid * 57) >> 9;
        const int kj = tid - ki * 9;
        valid_k = (rr_s[ki] > 0) && (cc_s[kj] > 0);
        float a = a_red[tid] + a_red[tid + 81] + a_red[tid + 162];
        a_val = valid_k ? a : -INFINITY;
        a_s[tid] = a_val;
    }
    __syncthreads();

    // ---- softmax over 81 (wave-0 butterfly) ----
    if (tid < 64) {
        float m = a_s[tid];
        if (tid + 64 < 81) m = fmaxf(m, a_s[tid + 64]);
        for (int o = 32; o >= 1; o >>= 1) m = fmaxf(m, __shfl_xor(m, o));
        if (tid == 0) m_sh = m;
    }
    __syncthreads();
    {
        float e = 0.f;
        if (tid < 81 && valid_k) e = expf(a_val - m_sh);
        if (tid < 81) e_s[tid] = e;
    }
    __syncthreads();
    if (tid < 64) {
        float sv = e_s[tid] + ((tid + 64 < 81) ? e_s[tid + 64] : 0.f);
        for (int o = 32; o >= 1; o >>= 1) sv += __shfl_xor(sv, o);
        if (tid == 0) inv_sh = 1.f / sv;
    }
    __syncthreads();
    if (tid < 81) {
        int i = (tid * 57) >> 9;
        int j = tid - i * 9;
        float g = expf(rex_s[i] + cex_s[j]);
        w_s[tid] = e_s[tid] * inv_sh * g;
    }
    __syncthreads();

    // ---- pass 2: out[d] = sum_k w_k * win[d][k] (LDS only) ----
    int posj[9];
#pragma unroll
    for (int j = 0; j < 9; j++) posj[j] = min(max(e0 + j - jc0, 0), 11);
    const _Float16* wd = &win[tid][0][0];
    float acc = 0.f;
#pragma unroll
    for (int k = 0; k < 81; k++) {
        const int ki = k / 9, kj = k % 9;         // compile-time
        acc = fmaf(w_s[k], (float)wd[ki * 12 + posj[kj]], acc);
    }
    out[(size_t)bt * Dd + tid] = acc;
}

extern "C" void kernel_launch(void* const* d_in, const int* in_sizes, int n_in,
                              void* d_out, int out_size, void* d_ws, size_t ws_size,
                              hipStream_t stream) {
    const float* q   = (const float*)d_in[0];
    const float* c_t = (const float*)d_in[1];
    const float* W_a = (const float*)d_in[2];
    const float* W_p = (const float*)d_in[3];
    const float* V_p = (const float*)d_in[4];
    float* out  = (float*)d_out;
    float* u_ws = (float*)d_ws;                       // 2 MB
    float* p_ws = u_ws + (size_t)NBT * Dd;            // 16 KB
    float* WpT  = p_ws + (size_t)NBT * 2;             // 512 KB

    transpose_wp<<<dim3(16, 8), 256, 0, stream>>>(W_p, WpT);
    prep_kernel<<<NBT / TOK, 512, 0, stream>>>(c_t, W_a, WpT, V_p, u_ws, p_ws);
    attn_kernel<<<NBT, 256, 0, stream>>>(q, u_ws, p_ws, out);
}

// Round 5
// 264.013 us; speedup vs baseline: 1.4032x; 1.0143x over previous
//
#include <hip/hip_runtime.h>
#include <math.h>

// Shapes (fixed): q(8,256,128,128) c_t(8,256,512) W_a(512,256) W_p(256,512) V_p(2,256)
#define Bq 8
#define Tt 256
#define Dd 256
#define Hh 128
#define Ww 128
#define Cc 512
#define HW (Hh*Ww)
#define NBT (Bq*Tt)   // 2048 tokens

__device__ __forceinline__ float lane_bcast(float x, int l) {
    return __uint_as_float(__builtin_amdgcn_readlane(__float_as_uint(x), l));
}

// ---------------- Kernel 0: transpose W_p (256x512) -> WpT (512x256) ------
__global__ __launch_bounds__(256) void transpose_wp(
    const float* __restrict__ W_p, float* __restrict__ WpT)
{
    __shared__ float tile[32][33];
    const int bx = blockIdx.x;            // c tile (16)
    const int by = blockIdx.y;            // p tile (8)
    const int lx = threadIdx.x & 31, ly = threadIdx.x >> 5;   // 32 x 8
#pragma unroll
    for (int j = 0; j < 4; j++) {
        int p = by * 32 + ly + j * 8;
        tile[ly + j * 8][lx] = W_p[(size_t)p * Cc + bx * 32 + lx];
    }
    __syncthreads();
#pragma unroll
    for (int j = 0; j < 4; j++) {
        int c = bx * 32 + ly + j * 8;
        WpT[(size_t)c * 256 + by * 32 + lx] = tile[lx][ly + j * 8];
    }
}

// ---------------- Kernel 1: u = c_t@W_a, p_t = 128*sig(V_p tanh(W_p c)) ---
// No broadcast loads: ct chunk lives in registers (1 coalesced load per
// token per 64-c chunk); lane->wave broadcast via v_readlane (VALU only).
// TOK=4 -> 512 blocks -> 2 blocks/CU, 4 waves/SIMD.
#define TOK 4
__global__ __launch_bounds__(512) void prep_kernel(
    const float* __restrict__ c_t,   // (NBT, 512)
    const float* __restrict__ W_a,   // (512, 256)  [c][d]
    const float* __restrict__ WpT,   // (512, 256)  [c][p]
    const float* __restrict__ V_p,   // (2, 256)
    float* __restrict__ u_ws,        // (NBT, 256)
    float* __restrict__ p_ws)        // (NBT, 2)
{
    __shared__ float y0s[TOK][256];
    __shared__ float y1s[TOK][256];
    const int tid  = threadIdx.x;
    const int o    = tid & 255;
    const int half = tid >> 8;
    const int ln   = tid & 63;
    const int bt0  = blockIdx.x * TOK;

    const float* Wcol = (half ? WpT : W_a) + o;   // column o, stride 256
    const float* ctb  = c_t + (size_t)bt0 * Cc;

    float acc[TOK];
#pragma unroll
    for (int t = 0; t < TOK; t++) acc[t] = 0.f;

    float ctr[TOK], ctn[TOK];
#pragma unroll
    for (int t = 0; t < TOK; t++) ctr[t] = ctb[t * Cc + ln];

#pragma unroll
    for (int c0 = 0; c0 < Cc; c0 += 64) {
        if (c0 + 64 < Cc) {
#pragma unroll
            for (int t = 0; t < TOK; t++) ctn[t] = ctb[t * Cc + c0 + 64 + ln];
        }
#pragma unroll
        for (int cc8 = 0; cc8 < 64; cc8 += 8) {
            float w[8];
#pragma unroll
            for (int j = 0; j < 8; j++)
                w[j] = Wcol[(size_t)(c0 + cc8 + j) * 256];
#pragma unroll
            for (int j = 0; j < 8; j++) {
#pragma unroll
                for (int t = 0; t < TOK; t++)
                    acc[t] = fmaf(lane_bcast(ctr[t], cc8 + j), w[j], acc[t]);
            }
        }
#pragma unroll
        for (int t = 0; t < TOK; t++) ctr[t] = ctn[t];
    }

    if (half == 0) {
#pragma unroll
        for (int t = 0; t < TOK; t++)
            u_ws[(size_t)(bt0 + t) * Dd + o] = acc[t];
    } else {
        float v0 = V_p[o], v1 = V_p[256 + o];
#pragma unroll
        for (int t = 0; t < TOK; t++) {
            float th = tanhf(acc[t]);
            y0s[t][o] = th * v0;
            y1s[t][o] = th * v1;
        }
    }
    __syncthreads();

    // 8 waves: wave w<4 reduces y0 of token w; wave w>=4 reduces y1 of w-4.
    const int wv = tid >> 6;
    const int t  = wv & 3;
    const float* ys = (wv < 4) ? &y0s[t][0] : &y1s[t][0];
    float s = ys[ln] + ys[ln + 64] + ys[ln + 128] + ys[ln + 192];
#pragma unroll
    for (int of = 32; of >= 1; of >>= 1) s += __shfl_xor(s, of);
    if (ln == 0)
        p_ws[(size_t)(bt0 + t) * 2 + ((wv < 4) ? 0 : 1)] = 128.f / (1.f + expf(-s));
}

// ---------------- Kernel 2: gather + fused scores + softmax + output ------
// One block per token. Loader computes partial scores while the float4 is
// in registers (fp32), stores fp16 stash for pass 2. No separate score pass.
__global__ __launch_bounds__(256) void attn_kernel(
    const float* __restrict__ q,     // (8,256,128,128)
    const float* __restrict__ u_ws,  // (NBT,256)
    const float* __restrict__ p_ws,  // (NBT,2)
    float* __restrict__ out)         // (NBT,256)
{
    __shared__ __align__(16) _Float16 win[Dd][9][12];   // 55296 B
    __shared__ __align__(16) float pacc_s[8][9][12];    // 3456 B
    __shared__ float ascore[9][12];
    __shared__ float u_s[Dd];
    __shared__ float w_s[81];
    __shared__ float a_s[81];
    __shared__ float e_s[81];
    __shared__ float rex_s[9], cex_s[9];
    __shared__ int   rr_s[9], cc_s[9];
    __shared__ float m_sh, inv_sh;

    const int tid = threadIdx.x;
    int bt = blockIdx.x;
    bt = ((bt & 7) << 8) | (bt >> 3);    // batch b -> XCD b (L2 affinity)
    const int b = bt >> 8;

    u_s[tid] = u_ws[(size_t)bt * Dd + tid];

    // zero-fill stash + score partials
    {
        float4* wf = (float4*)&win[0][0][0];
        for (int i = tid; i < 3456; i += 256) wf[i] = make_float4(0.f, 0.f, 0.f, 0.f);
        float* pz = &pacc_s[0][0][0];
        for (int i = tid; i < 864; i += 256) pz[i] = 0.f;
    }

    if (tid < 18) {
        int   i = (tid < 9) ? tid : tid - 9;
        float p = p_ws[(size_t)bt * 2 + ((tid < 9) ? 0 : 1)];
        int base = (int)rintf(p);                 // round-half-even = jnp.round
        int v = base + i - 3;                     // round(p)+off+1, off=i-4
        v = min(max(v, 0), 129) % 129;
        float cl = (float)max(v - 1, 0);
        float z  = (cl - p) * 0.25f;
        float ex = -2.f * z * z;
        if (tid < 9) { rr_s[i] = v; rex_s[i] = ex; }
        else         { cc_s[i] = v; cex_s[i] = ex; }
    }
    __syncthreads();

    // Valid cols form one contiguous run: derive aligned load base (uniform).
    int jc0 = 0, c0 = 1;
#pragma unroll
    for (int j = 8; j >= 0; j--)
        if (cc_s[j] > 0) { jc0 = j; c0 = cc_s[j]; }
    const int cb = min((c0 - 1) & ~3, Ww - 12);   // 12-float window covers run
    const int e0 = (c0 - 1) - cb;

    // ---- loader + fused partial scores ----
    {
        const int g  = tid >> 5;                  // d offset within 32-group
        const int l5 = tid & 31;
        const bool lact = (l5 < 27);
        const int li = lact ? ((l5 * 171) >> 9) : 0;   // l5/3
        const int lv = l5 - li * 3;
        const int vr = lact ? rr_s[li] : 0;
        const int rowoff = (max(vr, 1) - 1) * Ww + cb + 4 * lv;
        const float* qb = q + (size_t)b * Dd * HW;
        if (lact && vr > 0) {
            float px = 0.f, py = 0.f, pz = 0.f, pw = 0.f;
            for (int dd = 0; dd < Dd; dd += 32) {
                const int d0 = dd + g;
                float4 x0 = *(const float4*)(qb + (size_t)(d0     ) * HW + rowoff);
                float4 x1 = *(const float4*)(qb + (size_t)(d0 +  8) * HW + rowoff);
                float4 x2 = *(const float4*)(qb + (size_t)(d0 + 16) * HW + rowoff);
                float4 x3 = *(const float4*)(qb + (size_t)(d0 + 24) * HW + rowoff);
                float u0 = u_s[d0], u1 = u_s[d0 + 8], u2 = u_s[d0 + 16], u3 = u_s[d0 + 24];
                px = fmaf(x0.x, u0, px); py = fmaf(x0.y, u0, py);
                pz = fmaf(x0.z, u0, pz); pw = fmaf(x0.w, u0, pw);
                px = fmaf(x1.x, u1, px); py = fmaf(x1.y, u1, py);
                pz = fmaf(x1.z, u1, pz); pw = fmaf(x1.w, u1, pw);
                px = fmaf(x2.x, u2, px); py = fmaf(x2.y, u2, py);
                pz = fmaf(x2.z, u2, pz); pw = fmaf(x2.w, u2, pw);
                px = fmaf(x3.x, u3, px); py = fmaf(x3.y, u3, py);
                pz = fmaf(x3.z, u3, pz); pw = fmaf(x3.w, u3, pw);
                union { _Float16 h[4]; uint2 u; } p0, p1, p2, p3;
                p0.h[0] = (_Float16)x0.x; p0.h[1] = (_Float16)x0.y;
                p0.h[2] = (_Float16)x0.z; p0.h[3] = (_Float16)x0.w;
                p1.h[0] = (_Float16)x1.x; p1.h[1] = (_Float16)x1.y;
                p1.h[2] = (_Float16)x1.z; p1.h[3] = (_Float16)x1.w;
                p2.h[0] = (_Float16)x2.x; p2.h[1] = (_Float16)x2.y;
                p2.h[2] = (_Float16)x2.z; p2.h[3] = (_Float16)x2.w;
                p3.h[0] = (_Float16)x3.x; p3.h[1] = (_Float16)x3.y;
                p3.h[2] = (_Float16)x3.z; p3.h[3] = (_Float16)x3.w;
                *(uint2*)&win[d0     ][li][4 * lv] = p0.u;
                *(uint2*)&win[d0 +  8][li][4 * lv] = p1.u;
                *(uint2*)&win[d0 + 16][li][4 * lv] = p2.u;
                *(uint2*)&win[d0 + 24][li][4 * lv] = p3.u;
            }
            *(float4*)&pacc_s[g][li][4 * lv] = make_float4(px, py, pz, pw);
        }
    }
    __syncthreads();

    // ---- reduce partial scores over the 8 d-groups ----
    if (tid < 108) {
        const int li  = tid / 12;
        const int pos = tid - li * 12;
        float s = 0.f;
#pragma unroll
        for (int g = 0; g < 8; g++) s += pacc_s[g][li][pos];
        ascore[li][pos] = s;
    }
    __syncthreads();

    float a_val = -INFINITY;
    bool  valid_k = false;
    if (tid < 81) {
        const int ki = (tid * 57) >> 9;           // tid/9
        const int kj = tid - ki * 9;
        valid_k = (rr_s[ki] > 0) && (cc_s[kj] > 0);
        const int pos = min(max(e0 + kj - jc0, 0), 11);
        a_val = valid_k ? ascore[ki][pos] : -INFINITY;
        a_s[tid] = a_val;
    }
    __syncthreads();

    // ---- softmax over 81 (wave-0 butterfly) ----
    if (tid < 64) {
        float m = a_s[tid];
        if (tid + 64 < 81) m = fmaxf(m, a_s[tid + 64]);
        for (int o = 32; o >= 1; o >>= 1) m = fmaxf(m, __shfl_xor(m, o));
        if (tid == 0) m_sh = m;
    }
    __syncthreads();
    {
        float e = 0.f;
        if (tid < 81 && valid_k) e = expf(a_val - m_sh);
        if (tid < 81) e_s[tid] = e;
    }
    __syncthreads();
    if (tid < 64) {
        float sv = e_s[tid] + ((tid + 64 < 81) ? e_s[tid + 64] : 0.f);
        for (int o = 32; o >= 1; o >>= 1) sv += __shfl_xor(sv, o);
        if (tid == 0) inv_sh = 1.f / sv;
    }
    __syncthreads();
    if (tid < 81) {
        int i = (tid * 57) >> 9;
        int j = tid - i * 9;
        float g = expf(rex_s[i] + cex_s[j]);
        w_s[tid] = e_s[tid] * inv_sh * g;
    }
    __syncthreads();

    // ---- pass 2: out[d] = sum_k w_k * win[d][k] (LDS only) ----
    int posj[9];
#pragma unroll
    for (int j = 0; j < 9; j++) posj[j] = min(max(e0 + j - jc0, 0), 11);
    const _Float16* wd = &win[tid][0][0];
    float acc = 0.f;
#pragma unroll
    for (int k = 0; k < 81; k++) {
        const int ki = k / 9, kj = k % 9;         // compile-time
        acc = fmaf(w_s[k], (float)wd[ki * 12 + posj[kj]], acc);
    }
    out[(size_t)bt * Dd + tid] = acc;
}

extern "C" void kernel_launch(void* const* d_in, const int* in_sizes, int n_in,
                              void* d_out, int out_size, void* d_ws, size_t ws_size,
                              hipStream_t stream) {
    const float* q   = (const float*)d_in[0];
    const float* c_t = (const float*)d_in[1];
    const float* W_a = (const float*)d_in[2];
    const float* W_p = (const float*)d_in[3];
    const float* V_p = (const float*)d_in[4];
    float* out  = (float*)d_out;
    float* u_ws = (float*)d_ws;                       // 2 MB
    float* p_ws = u_ws + (size_t)NBT * Dd;            // 16 KB
    float* WpT  = p_ws + (size_t)NBT * 2;             // 512 KB

    transpose_wp<<<dim3(16, 8), 256, 0, stream>>>(W_p, WpT);
    prep_kernel<<<NBT / TOK, 512, 0, stream>>>(c_t, W_a, WpT, V_p, u_ws, p_ws);
    attn_kernel<<<NBT, 256, 0, stream>>>(q, u_ws, p_ws, out);
}

// Round 6
// 262.983 us; speedup vs baseline: 1.4087x; 1.0039x over previous
//
#include <hip/hip_runtime.h>
#include <math.h>

// Shapes (fixed): q(8,256,128,128) c_t(8,256,512) W_a(512,256) W_p(256,512) V_p(2,256)
#define Bq 8
#define Tt 256
#define Dd 256
#define Hh 128
#define Ww 128
#define Cc 512
#define HW (Hh*Ww)
#define NBT (Bq*Tt)   // 2048 tokens

__device__ __forceinline__ float lane_bcast(float x, int l) {
    return __uint_as_float(__builtin_amdgcn_readlane(__float_as_uint(x), l));
}

// ---------------- Kernel 0: transpose W_p (256x512) -> WpT (512x256) ------
__global__ __launch_bounds__(256) void transpose_wp(
    const float* __restrict__ W_p, float* __restrict__ WpT)
{
    __shared__ float tile[32][33];
    const int bx = blockIdx.x;            // c tile (16)
    const int by = blockIdx.y;            // p tile (8)
    const int lx = threadIdx.x & 31, ly = threadIdx.x >> 5;   // 32 x 8
#pragma unroll
    for (int j = 0; j < 4; j++) {
        int p = by * 32 + ly + j * 8;
        tile[ly + j * 8][lx] = W_p[(size_t)p * Cc + bx * 32 + lx];
    }
    __syncthreads();
#pragma unroll
    for (int j = 0; j < 4; j++) {
        int c = bx * 32 + ly + j * 8;
        WpT[(size_t)c * 256 + by * 32 + lx] = tile[lx][ly + j * 8];
    }
}

// ---------------- Kernel 1: u = c_t@W_a, p_t = 128*sig(V_p tanh(W_p c)) ---
// TOK=8 -> 256 blocks (1/CU, 8 waves). ct chunks in registers, lane->wave
// broadcast via v_readlane (VALU only, no memory-pipe broadcasts).
#define TOK 8
__global__ __launch_bounds__(512) void prep_kernel(
    const float* __restrict__ c_t,   // (NBT, 512)
    const float* __restrict__ W_a,   // (512, 256)  [c][d]
    const float* __restrict__ WpT,   // (512, 256)  [c][p]
    const float* __restrict__ V_p,   // (2, 256)
    float* __restrict__ u_ws,        // (NBT, 256)
    float* __restrict__ p_ws)        // (NBT, 2)
{
    __shared__ float y0s[TOK][256];
    __shared__ float y1s[TOK][256];
    const int tid  = threadIdx.x;
    const int o    = tid & 255;
    const int half = tid >> 8;
    const int ln   = tid & 63;
    const int bt0  = blockIdx.x * TOK;

    const float* Wcol = (half ? WpT : W_a) + o;   // column o, stride 256
    const float* ctb  = c_t + (size_t)bt0 * Cc;

    float acc[TOK];
#pragma unroll
    for (int t = 0; t < TOK; t++) acc[t] = 0.f;

    float ctr[TOK], ctn[TOK];
#pragma unroll
    for (int t = 0; t < TOK; t++) ctr[t] = ctb[t * Cc + ln];

#pragma unroll
    for (int c0 = 0; c0 < Cc; c0 += 64) {
        if (c0 + 64 < Cc) {
#pragma unroll
            for (int t = 0; t < TOK; t++) ctn[t] = ctb[t * Cc + c0 + 64 + ln];
        }
#pragma unroll
        for (int cc8 = 0; cc8 < 64; cc8 += 8) {
            float w[8];
#pragma unroll
            for (int j = 0; j < 8; j++)
                w[j] = Wcol[(size_t)(c0 + cc8 + j) * 256];
#pragma unroll
            for (int j = 0; j < 8; j++) {
#pragma unroll
                for (int t = 0; t < TOK; t++)
                    acc[t] = fmaf(lane_bcast(ctr[t], cc8 + j), w[j], acc[t]);
            }
        }
#pragma unroll
        for (int t = 0; t < TOK; t++) ctr[t] = ctn[t];
    }

    if (half == 0) {
#pragma unroll
        for (int t = 0; t < TOK; t++)
            u_ws[(size_t)(bt0 + t) * Dd + o] = acc[t];
    } else {
        float v0 = V_p[o], v1 = V_p[256 + o];
#pragma unroll
        for (int t = 0; t < TOK; t++) {
            float th = tanhf(acc[t]);
            y0s[t][o] = th * v0;
            y1s[t][o] = th * v1;
        }
    }
    __syncthreads();

    // 8 waves: wave w reduces token w (both outputs).
    const int wv = tid >> 6;
    float s0 = y0s[wv][ln] + y0s[wv][ln + 64] + y0s[wv][ln + 128] + y0s[wv][ln + 192];
    float s1 = y1s[wv][ln] + y1s[wv][ln + 64] + y1s[wv][ln + 128] + y1s[wv][ln + 192];
#pragma unroll
    for (int of = 32; of >= 1; of >>= 1) {
        s0 += __shfl_xor(s0, of);
        s1 += __shfl_xor(s1, of);
    }
    if (ln == 0) {
        p_ws[(size_t)(bt0 + wv) * 2 + 0] = 128.f / (1.f + expf(-s0));
        p_ws[(size_t)(bt0 + wv) * 2 + 1] = 128.f / (1.f + expf(-s1));
    }
}

// ---------------- Kernel 2: gather + fused scores + softmax + output ------
// One block per token. 2-stage pipelined loader (8 float4 in flight),
// u preloaded to registers, no zero-fills (invalid rows load row 0 and are
// nulled by the -inf / w=0 masking).
__global__ __launch_bounds__(256) void attn_kernel(
    const float* __restrict__ q,     // (8,256,128,128)
    const float* __restrict__ u_ws,  // (NBT,256)
    const float* __restrict__ p_ws,  // (NBT,2)
    float* __restrict__ out)         // (NBT,256)
{
    __shared__ __align__(16) _Float16 win[Dd][9][12];   // 55296 B
    __shared__ __align__(16) float pacc_s[8][9][12];    // 3456 B
    __shared__ float ascore[9][12];
    __shared__ float u_s[Dd];
    __shared__ float w_s[81];
    __shared__ float a_s[81];
    __shared__ float e_s[81];
    __shared__ float rex_s[9], cex_s[9];
    __shared__ int   rr_s[9], cc_s[9];
    __shared__ float m_sh, inv_sh;

    const int tid = threadIdx.x;
    int bt = blockIdx.x;
    bt = ((bt & 7) << 8) | (bt >> 3);    // batch b -> XCD b (L2 affinity)
    const int b = bt >> 8;

    u_s[tid] = u_ws[(size_t)bt * Dd + tid];

    if (tid < 18) {
        int   i = (tid < 9) ? tid : tid - 9;
        float p = p_ws[(size_t)bt * 2 + ((tid < 9) ? 0 : 1)];
        int base = (int)rintf(p);                 // round-half-even = jnp.round
        int v = base + i - 3;                     // round(p)+off+1, off=i-4
        v = min(max(v, 0), 129) % 129;
        float cl = (float)max(v - 1, 0);
        float z  = (cl - p) * 0.25f;
        float ex = -2.f * z * z;
        if (tid < 9) { rr_s[i] = v; rex_s[i] = ex; }
        else         { cc_s[i] = v; cex_s[i] = ex; }
    }
    __syncthreads();

    // Valid cols form one contiguous run: derive aligned load base (uniform).
    int jc0 = 0, c0 = 1;
#pragma unroll
    for (int j = 8; j >= 0; j--)
        if (cc_s[j] > 0) { jc0 = j; c0 = cc_s[j]; }
    const int cb = min((c0 - 1) & ~3, Ww - 12);   // 12-float window covers run
    const int e0 = (c0 - 1) - cb;

    // ---- pipelined loader + fused partial scores ----
    {
        const int g  = tid >> 5;                  // 0..7
        const int l5 = tid & 31;
        const bool lact = (l5 < 27);
        const int li = lact ? ((l5 * 171) >> 9) : 0;   // l5/3
        const int lv = l5 - li * 3;
        const int vr = lact ? rr_s[li] : 1;
        const int rowoff = (max(vr, 1) - 1) * Ww + cb + 4 * lv;
        const float* qp = q + (size_t)b * Dd * HW + rowoff;

        if (lact) {
            // preload the 32 u values this lane consumes (d = g + 8m)
            float u_r[32];
#pragma unroll
            for (int m = 0; m < 32; m++) u_r[m] = u_s[g + 8 * m];

            float px = 0.f, py = 0.f, pz = 0.f, pw = 0.f;
            float4 xb[2][4];
#pragma unroll
            for (int mm = 0; mm < 4; mm++)
                xb[0][mm] = *(const float4*)(qp + (size_t)(g + 8 * mm) * HW);

            for (int it = 0; it < 8; it++) {
                const int cur = it & 1;
                if (it < 7) {
#pragma unroll
                    for (int mm = 0; mm < 4; mm++)
                        xb[cur ^ 1][mm] = *(const float4*)
                            (qp + (size_t)(g + 8 * (4 * (it + 1) + mm)) * HW);
                }
#pragma unroll
                for (int mm = 0; mm < 4; mm++) {
                    const int m  = 4 * it + mm;
                    const int d0 = g + 8 * m;
                    float4 x = xb[cur][mm];
                    float  u = u_r[m];
                    px = fmaf(x.x, u, px); py = fmaf(x.y, u, py);
                    pz = fmaf(x.z, u, pz); pw = fmaf(x.w, u, pw);
                    union { _Float16 h[4]; uint2 uu; } pk;
                    pk.h[0] = (_Float16)x.x; pk.h[1] = (_Float16)x.y;
                    pk.h[2] = (_Float16)x.z; pk.h[3] = (_Float16)x.w;
                    *(uint2*)&win[d0][li][4 * lv] = pk.uu;
                }
            }
            *(float4*)&pacc_s[g][li][4 * lv] = make_float4(px, py, pz, pw);
        }
    }
    __syncthreads();

    // ---- reduce partial scores over the 8 d-groups ----
    if (tid < 108) {
        const int li  = tid / 12;
        const int pos = tid - li * 12;
        float s = 0.f;
#pragma unroll
        for (int g = 0; g < 8; g++) s += pacc_s[g][li][pos];
        ascore[li][pos] = s;
    }
    __syncthreads();

    float a_val = -INFINITY;
    bool  valid_k = false;
    if (tid < 81) {
        const int ki = (tid * 57) >> 9;           // tid/9
        const int kj = tid - ki * 9;
        valid_k = (rr_s[ki] > 0) && (cc_s[kj] > 0);
        const int pos = min(max(e0 + kj - jc0, 0), 11);
        a_val = valid_k ? ascore[ki][pos] : -INFINITY;
        a_s[tid] = a_val;
    }
    __syncthreads();

    // ---- softmax over 81 (wave-0 butterfly) ----
    if (tid < 64) {
        float m = a_s[tid];
        if (tid + 64 < 81) m = fmaxf(m, a_s[tid + 64]);
        for (int o = 32; o >= 1; o >>= 1) m = fmaxf(m, __shfl_xor(m, o));
        if (tid == 0) m_sh = m;
    }
    __syncthreads();
    {
        float e = 0.f;
        if (tid < 81 && valid_k) e = expf(a_val - m_sh);
        if (tid < 81) e_s[tid] = e;
    }
    __syncthreads();
    if (tid < 64) {
        float sv = e_s[tid] + ((tid + 64 < 81) ? e_s[tid + 64] : 0.f);
        for (int o = 32; o >= 1; o >>= 1) sv += __shfl_xor(sv, o);
        if (tid == 0) inv_sh = 1.f / sv;
    }
    __syncthreads();
    if (tid < 81) {
        int i = (tid * 57) >> 9;
        int j = tid - i * 9;
        float g = expf(rex_s[i] + cex_s[j]);
        w_s[tid] = e_s[tid] * inv_sh * g;
    }
    __syncthreads();

    // ---- pass 2: out[d] = sum_k w_k * win[d][k] (LDS only) ----
    int posj[9];
#pragma unroll
    for (int j = 0; j < 9; j++) posj[j] = min(max(e0 + j - jc0, 0), 11);
    const _Float16* wd = &win[tid][0][0];
    float acc = 0.f;
#pragma unroll
    for (int k = 0; k < 81; k++) {
        const int ki = k / 9, kj = k % 9;         // compile-time
        acc = fmaf(w_s[k], (float)wd[ki * 12 + posj[kj]], acc);
    }
    out[(size_t)bt * Dd + tid] = acc;
}

extern "C" void kernel_launch(void* const* d_in, const int* in_sizes, int n_in,
                              void* d_out, int out_size, void* d_ws, size_t ws_size,
                              hipStream_t stream) {
    const float* q   = (const float*)d_in[0];
    const float* c_t = (const float*)d_in[1];
    const float* W_a = (const float*)d_in[2];
    const float* W_p = (const float*)d_in[3];
    const float* V_p = (const float*)d_in[4];
    float* out  = (float*)d_out;
    float* u_ws = (float*)d_ws;                       // 2 MB
    float* p_ws = u_ws + (size_t)NBT * Dd;            // 16 KB
    float* WpT  = p_ws + (size_t)NBT * 2;             // 512 KB

    transpose_wp<<<dim3(16, 8), 256, 0, stream>>>(W_p, WpT);
    prep_kernel<<<NBT / TOK, 512, 0, stream>>>(c_t, W_a, WpT, V_p, u_ws, p_ws);
    attn_kernel<<<NBT, 256, 0, stream>>>(q, u_ws, p_ws, out);
}